// Round 3
// baseline (227.490 us; speedup 1.0000x reference)
//
#include <hip/hip_runtime.h>
#include <hip/hip_bf16.h>

// Problem constants (reference: B=2, S=2048, D=1024, H=16, HD=64)
#define BB 2
#define SS 2048
#define DD 1024
#define HH 16
#define HD 64
#define MM (BB * SS)   // 4096 rows in all GEMMs
#define NQKV 3072      // fused QKV output columns

typedef __attribute__((ext_vector_type(8))) short short8;   // 8 x bf16 frag
typedef __attribute__((ext_vector_type(4))) short s16x4;
typedef __attribute__((ext_vector_type(4))) float floatx4;  // MFMA C/D frag
typedef __attribute__((ext_vector_type(4))) float f32x4;
using bf16 = __hip_bfloat16;

__device__ __forceinline__ float b2f(bf16 x) { return __bfloat162float(x); }
__device__ __forceinline__ short f2bs(float x) {
    bf16 h = __float2bfloat16(x);
    return *reinterpret_cast<short*>(&h);
}
__device__ __forceinline__ float bs2f(short s) {
    bf16 h; *reinterpret_cast<short*>(&h) = s; return __bfloat162float(h);
}

// LDS tiles addressed in 16B chunks (8 shorts), XOR swizzle (chunk ^ (row&7)).
// Measured SQ_LDS_BANK_CONFLICT == 0 with this pattern (r13 counters).
__device__ __forceinline__ int lds_off(int row, int chunk) {
    return row * 64 + ((chunk ^ (row & 7)) * 8);
}

// Direct global->LDS async copy, 16B per lane. LDS dest is wave-uniform base
// + lane*16 (linear); the XOR swizzle is applied on the GLOBAL source address.
#define GL16(gp, lp)                                                        \
    __builtin_amdgcn_global_load_lds(                                       \
        (const __attribute__((address_space(1))) void*)(gp),                \
        (__attribute__((address_space(3))) void*)(lp), 16, 0, 0)

// ---------------------------------------------------------------------------
// Weight / input converters (unchanged).
// ---------------------------------------------------------------------------
__global__ __launch_bounds__(256) void convert_wcat(
    const float* __restrict__ Wq, const float* __restrict__ Wk,
    const float* __restrict__ Wv, short* __restrict__ dst)
{
    const int stride = gridDim.x * blockDim.x;
    for (int i = blockIdx.x * blockDim.x + threadIdx.x; i < NQKV * DD / 4; i += stride) {
        const int elem = i * 4;
        const int z    = elem >> 20;
        const int off  = elem & 0xFFFFF;
        const float* src = (z == 0) ? Wq : (z == 1) ? Wk : Wv;
        f32x4 v = *(const f32x4*)(src + off);
        s16x4 o; o[0] = f2bs(v[0]); o[1] = f2bs(v[1]); o[2] = f2bs(v[2]); o[3] = f2bs(v[3]);
        *(s16x4*)(dst + elem) = o;
    }
}

__global__ __launch_bounds__(256) void convert_w(
    const float* __restrict__ W, short* __restrict__ dst)
{
    const int stride = gridDim.x * blockDim.x;
    for (int i = blockIdx.x * blockDim.x + threadIdx.x; i < DD * DD / 4; i += stride) {
        f32x4 v = *(const f32x4*)(W + i * 4);
        s16x4 o; o[0] = f2bs(v[0]); o[1] = f2bs(v[1]); o[2] = f2bs(v[2]); o[3] = f2bs(v[3]);
        *(s16x4*)(dst + i * 4) = o;
    }
}

__global__ __launch_bounds__(256) void convert_x(
    const float* __restrict__ X, short* __restrict__ dst)
{
    const int stride = gridDim.x * blockDim.x;
    for (int i = blockIdx.x * blockDim.x + threadIdx.x; i < MM * DD / 4; i += stride) {
        f32x4 v = *(const f32x4*)(X + i * 4);
        s16x4 o; o[0] = f2bs(v[0]); o[1] = f2bs(v[1]); o[2] = f2bs(v[2]); o[3] = f2bs(v[3]);
        *(s16x4*)(dst + i * 4) = o;
    }
}

// ---------------------------------------------------------------------------
// Fused QKV GEMM, r15: 256x256 8-phase, QUADRANT-MAJOR read mapping (r14 race
// fix). Phase (MH,NH) reads ONLY A-half MH (rows MH*128..+127, wave offset
// wm*64) and B-half NH (rows NH*128..+127, wave offset wn*32). Overwrite
// windows (stage into a half only after its last reader phase completed):
//   A.h0 last read p2 -> stage p3 | B.h0 last read p3 -> stage p4
//   A.h1/B.h1 last read p4 -> stage p5 | buf1 symmetric (p7/p8/next-p1/p2)
// Stage schedule per iteration j (unchanged from r14; gates vmcnt(4)):
//   p1: buf1.Ah1<-2j+1 (skip j=0)  p2: buf1.Bh1<-2j+1
//   p3: buf0.Ah0<-2j+2             p4: buf0.Bh0<-2j+2 ; vmcnt(4)
//   p5: buf0.Ah1<-2j+2             p6: buf0.Bh1<-2j+2
//   p7: buf1.Ah0<-2j+3             p8: buf1.Bh0<-2j+3 ; vmcnt(4)
// p4 gate retires {prev p7,p8,p1,p2} = buf1 tile 2j+1 before p5 reads it;
// p8 gate retires {p3..p6} = buf0 tile 2j+2 before next-iter p1 reads it.
// ---------------------------------------------------------------------------
template <int D, int MH, int NH, class Stage, class Tail>
__device__ __forceinline__ void phase8(
    const short* As, const short* Bs, int wm, int wn, int fr, int g,
    floatx4 (&acc)[8][4], Stage&& stage, Tail&& tail)
{
    short8 af[4][2], bfq[2][2];
    const short* Ad = As + D * (256 * 64);
    const short* Bd = Bs + D * (256 * 64);
#pragma unroll
    for (int t = 0; t < 4; ++t)
#pragma unroll
        for (int kk = 0; kk < 2; ++kk)
            af[t][kk] = *(const short8*)&Ad[lds_off(MH * 128 + wm * 64 + t * 16 + fr, kk * 4 + g)];
#pragma unroll
    for (int u = 0; u < 2; ++u)
#pragma unroll
        for (int kk = 0; kk < 2; ++kk)
            bfq[u][kk] = *(const short8*)&Bd[lds_off(NH * 128 + wn * 32 + u * 16 + fr, kk * 4 + g)];
    stage();
    __builtin_amdgcn_s_barrier();
    asm volatile("s_waitcnt lgkmcnt(0)" ::: "memory");
    __builtin_amdgcn_s_setprio(1);
#pragma unroll
    for (int t = 0; t < 4; ++t)
#pragma unroll
        for (int u = 0; u < 2; ++u) {
            acc[MH * 4 + t][NH * 2 + u] = __builtin_amdgcn_mfma_f32_16x16x32_bf16(
                af[t][0], bfq[u][0], acc[MH * 4 + t][NH * 2 + u], 0, 0, 0);
            acc[MH * 4 + t][NH * 2 + u] = __builtin_amdgcn_mfma_f32_16x16x32_bf16(
                af[t][1], bfq[u][1], acc[MH * 4 + t][NH * 2 + u], 0, 0, 0);
        }
    __builtin_amdgcn_s_setprio(0);
    tail();
    __builtin_amdgcn_s_barrier();
}

__global__ __launch_bounds__(512, 2) void qkv_gemm8(
    const short* __restrict__ Xb, const short* __restrict__ Wcat,
    const float* __restrict__ bq, const float* __restrict__ bk, const float* __restrict__ bv,
    bf16* __restrict__ outQ, bf16* __restrict__ outK, bf16* __restrict__ outV)
{
    extern __shared__ short lds[];
    short* As = lds;                   // [2][256*64]
    short* Bs = lds + 2 * 256 * 64;    // [2][256*64]

    const int tid  = threadIdx.x;
    const int lane = tid & 63;
    const int wave = tid >> 6;     // 0..7
    const int wm   = wave >> 2;    // 0..1  (M sub-block within a quadrant)
    const int wn   = wave & 3;     // 0..3  (N sub-block within a quadrant)
    const int g    = lane >> 4;
    const int fr   = lane & 15;

    // XCD-aware swizzle: 192 blocks, 24 per XCD chunk (bijective, 192%8==0).
    const int sw = (blockIdx.x & 7) * 24 + (blockIdx.x >> 3);
    const int m0 = (sw % 16) * 256;
    const int n0 = (sw / 16) * 256;

    const int srow8 = lane >> 3;            // 0..7
    const int schk  = (lane & 7) ^ srow8;   // pre-swizzled source chunk

    // stage one half (128 rows x 64 k) of A or B into buf d, half h, K-tile kt.
    auto stageA = [&](int d, int h, int kt) {
#pragma unroll
        for (int j = 0; j < 2; ++j) {
            const int r = h * 128 + wave * 16 + j * 8;
            const short* src = Xb + (size_t)(m0 + r + srow8) * DD + kt * 64 + schk * 8;
            GL16(src, As + d * (256 * 64) + r * 64);
        }
    };
    auto stageB = [&](int d, int h, int kt) {
#pragma unroll
        for (int j = 0; j < 2; ++j) {
            const int r = h * 128 + wave * 16 + j * 8;
            const short* src = Wcat + (size_t)(n0 + r + srow8) * DD + kt * 64 + schk * 8;
            GL16(src, Bs + d * (256 * 64) + r * 64);
        }
    };

    floatx4 acc[8][4];
#pragma unroll
    for (int i = 0; i < 8; ++i)
#pragma unroll
        for (int j = 0; j < 4; ++j) acc[i][j] = (floatx4){0.f, 0.f, 0.f, 0.f};

    // Prologue: fully stage tiles 0 (buf0) and 1 (buf1).
    stageA(0, 0, 0); stageA(0, 1, 0); stageB(0, 0, 0); stageB(0, 1, 0);
    stageA(1, 0, 1); stageA(1, 1, 1); stageB(1, 0, 1); stageB(1, 1, 1);
    asm volatile("s_waitcnt vmcnt(0)" ::: "memory");
    __builtin_amdgcn_s_barrier();

    auto nop = [] {};
    auto vm4 = [] { asm volatile("s_waitcnt vmcnt(4)" ::: "memory"); };

    for (int it = 0; it < 8; ++it) {
        const int t1 = (2 * it + 1) & 15;
        const int s2 = (2 * it + 2) & 15;   // wraps harmlessly on last iter
        const int s3 = (2 * it + 3) & 15;
        phase8<0, 0, 0>(As, Bs, wm, wn, fr, g, acc,
                        [&] { if (it) stageA(1, 1, t1); }, nop);
        phase8<0, 0, 1>(As, Bs, wm, wn, fr, g, acc,
                        [&] { if (it) stageB(1, 1, t1); }, nop);
        phase8<0, 1, 0>(As, Bs, wm, wn, fr, g, acc,
                        [&] { stageA(0, 0, s2); }, nop);
        phase8<0, 1, 1>(As, Bs, wm, wn, fr, g, acc,
                        [&] { stageB(0, 0, s2); }, vm4);
        phase8<1, 0, 0>(As, Bs, wm, wn, fr, g, acc,
                        [&] { stageA(0, 1, s2); }, nop);
        phase8<1, 0, 1>(As, Bs, wm, wn, fr, g, acc,
                        [&] { stageB(0, 1, s2); }, nop);
        phase8<1, 1, 0>(As, Bs, wm, wn, fr, g, acc,
                        [&] { stageA(1, 0, s3); }, nop);
        phase8<1, 1, 1>(As, Bs, wm, wn, fr, g, acc,
                        [&] { stageB(1, 0, s3); }, vm4);
    }

    // Epilogue: quadrant-major index mapping.
    //   m = m0 + (mt>>2)*128 + wm*64 + (mt&3)*16 + g*4 + reg
    //   n = n0 + (nt>>1)*128 + wn*32 + (nt&1)*16 + fr
#pragma unroll
    for (int nt = 0; nt < 4; ++nt) {
        const int n  = n0 + (nt >> 1) * 128 + wn * 32 + (nt & 1) * 16 + fr;
        const int z  = n >> 10;
        const int nn = n & 1023;
        const int h_ = nn >> 6;
        const int d_ = nn & 63;
        const float biasv = ((z == 0) ? bq : (z == 1) ? bk : bv)[nn];
        bf16* outp = (z == 0) ? outQ : (z == 1) ? outK : outV;
#pragma unroll
        for (int mt = 0; mt < 8; ++mt) {
#pragma unroll
            for (int reg = 0; reg < 4; ++reg) {
                const int m  = m0 + (mt >> 2) * 128 + wm * 64 + (mt & 3) * 16 + g * 4 + reg;
                const int b_ = m >> 11;
                const int s_ = m & (SS - 1);
                const float v = acc[mt][nt][reg] + biasv;
                size_t off;
                if (z == 2) off = ((size_t)((b_ * HH + h_) * HD + d_)) * SS + s_;  // V^T
                else        off = ((size_t)((b_ * HH + h_) * SS + s_)) * HD + d_;  // Q,K
                outp[off] = __float2bfloat16(v);
            }
        }
    }
}

// ---------------------------------------------------------------------------
// Output projection (r13 structure, unchanged: global_load_lds, 128^2 tile).
// ---------------------------------------------------------------------------
__global__ __launch_bounds__(256) void o_gemm2(
    const short* __restrict__ A, const short* __restrict__ Wob,
    const float* __restrict__ bias, float* __restrict__ out)
{
    __shared__ short As[128 * 64];
    __shared__ short Bs[128 * 64];

    const int tid  = threadIdx.x;
    const int lane = tid & 63;
    const int wave = tid >> 6;
    const int wm   = wave & 1;
    const int wn   = wave >> 1;
    const int g    = lane >> 4;
    const int fr   = lane & 15;

    const int m0 = blockIdx.x * 128;
    const int n0 = blockIdx.y * 128;

    const int srow = wave * 32 + (lane >> 3);
    const int schk = (lane & 7) ^ (lane >> 3);
    const short* agl = A   + (size_t)(m0 + srow) * DD + schk * 8;
    const short* bgl = Wob + (size_t)(n0 + srow) * DD + schk * 8;
    short* alds = &As[wave * 32 * 64];
    short* blds = &Bs[wave * 32 * 64];

    floatx4 acc[4][4];
#pragma unroll
    for (int i = 0; i < 4; ++i)
#pragma unroll
        for (int j = 0; j < 4; ++j) acc[i][j] = (floatx4){0.f, 0.f, 0.f, 0.f};

    for (int kb = 0; kb < DD; kb += 64) {
        __syncthreads();
#pragma unroll
        for (int j = 0; j < 4; ++j) {
            GL16(agl + kb + j * 8 * DD, alds + j * 8 * 64);
            GL16(bgl + kb + j * 8 * DD, blds + j * 8 * 64);
        }
        __syncthreads();

#pragma unroll
        for (int kk = 0; kk < 2; ++kk) {
            const int kc = kk * 4 + g;
            short8 af[4], bf[4];
#pragma unroll
            for (int t = 0; t < 4; ++t) {
                af[t] = *(const short8*)&As[lds_off(wm * 64 + t * 16 + fr, kc)];
                bf[t] = *(const short8*)&Bs[lds_off(wn * 64 + t * 16 + fr, kc)];
            }
#pragma unroll
            for (int mt = 0; mt < 4; ++mt)
#pragma unroll
                for (int nt = 0; nt < 4; ++nt)
                    acc[mt][nt] = __builtin_amdgcn_mfma_f32_16x16x32_bf16(
                        af[mt], bf[nt], acc[mt][nt], 0, 0, 0);
        }
    }

#pragma unroll
    for (int nt = 0; nt < 4; ++nt) {
        const int n = n0 + wn * 64 + nt * 16 + fr;
        const float biasv = bias[n];
#pragma unroll
        for (int mt = 0; mt < 4; ++mt) {
#pragma unroll
            for (int reg = 0; reg < 4; ++reg) {
                const int m = m0 + wm * 64 + mt * 16 + g * 4 + reg;
                out[(size_t)m * DD + n] = acc[mt][nt][reg] + biasv;
            }
        }
    }
}

// ---------------------------------------------------------------------------
// MFMA flash attention v5 (unchanged).
// ---------------------------------------------------------------------------
__global__ __launch_bounds__(256) void flash_mfma5(
    const bf16* __restrict__ Qh,   // [B,H,S,HD]
    const bf16* __restrict__ Kh,   // [B,H,S,HD]
    const bf16* __restrict__ VT,   // [B,H,HD,S]
    const int*  __restrict__ pad,  // [B,S] int32, nonzero = masked key
    bf16* __restrict__ attn)       // [B,S,D]
{
    __shared__ short Ks[64 * 64];
    __shared__ short Vs[64 * 64];
    __shared__ short Pld[4][16 * 64];

    const int tid  = threadIdx.x;
    const int lane = tid & 63;
    const int wave = tid >> 6;
    const int xcd = blockIdx.x & 7;
    const int idx = blockIdx.x >> 3;
    const int bh  = (xcd << 2) | (idx & 3);
    const int qt  = 31 - (idx >> 2);
    const int q0  = qt * 64 + wave * 16;
    const int b_  = bh >> 4;
    const int h_  = bh & 15;

    const int g  = lane >> 4;
    const int fr = lane & 15;
    const int k8 = g * 8;

    short* myP = Pld[wave];

    const bf16* qbase = Qh + ((size_t)bh * SS + q0 + fr) * HD + k8;
    short8 qf[2];
#pragma unroll
    for (int hh = 0; hh < 2; ++hh) {
        short8 rawq = *(const short8*)((const short*)qbase + hh * 32);
#pragma unroll
        for (int j = 0; j < 8; ++j) qf[hh][j] = f2bs(bs2f(rawq[j]) * 0.125f);
    }

    const int* padrow = pad + b_ * SS;
    const short* kbh = (const short*)(Kh + (size_t)bh * SS * HD);
    const short* vbh = (const short*)(VT + (size_t)bh * HD * SS);

    const int sr = tid >> 2;
    const int cp = (tid & 3) * 2;

    floatx4 o[4] = {{0,0,0,0},{0,0,0,0},{0,0,0,0},{0,0,0,0}};
    float l_acc[4] = {0.f, 0.f, 0.f, 0.f};

    const int kend = qt * 64 + 63;
    for (int kb = 0; kb <= kend; kb += 64) {
        __syncthreads();
        {
            const short* gk = kbh + (size_t)(kb + sr) * HD + cp * 8;
            *(short8*)&Ks[lds_off(sr, cp)]     = *(const short8*)gk;
            *(short8*)&Ks[lds_off(sr, cp + 1)] = *(const short8*)(gk + 8);
            const short* gv = vbh + (size_t)sr * SS + kb + cp * 8;
            *(short8*)&Vs[lds_off(sr, cp)]     = *(const short8*)gv;
            *(short8*)&Vs[lds_off(sr, cp + 1)] = *(const short8*)(gv + 8);
        }
        __syncthreads();

        floatx4 c[4];
#pragma unroll
        for (int t = 0; t < 4; ++t) {
            short8 kf0 = *(const short8*)&Ks[(t * 16 + fr) * 64 + ((g       ^ (fr & 7)) << 3)];
            short8 kf1 = *(const short8*)&Ks[(t * 16 + fr) * 64 + (((g + 4) ^ (fr & 7)) << 3)];
            floatx4 cc = {0, 0, 0, 0};
            cc = __builtin_amdgcn_mfma_f32_16x16x32_bf16(qf[0], kf0, cc, 0, 0, 0);
            cc = __builtin_amdgcn_mfma_f32_16x16x32_bf16(qf[1], kf1, cc, 0, 0, 0);
            c[t] = cc;
        }

        bool pm[4];
#pragma unroll
        for (int t = 0; t < 4; ++t) pm[t] = (padrow[kb + t * 16 + fr] != 0);

#pragma unroll
        for (int reg = 0; reg < 4; ++reg) {
            const int q   = q0 + g * 4 + reg;
            const int row = g * 4 + reg;
#pragma unroll
            for (int t = 0; t < 4; ++t) {
                const int key = kb + t * 16 + fr;
                const float p = (key <= q && !pm[t]) ? __expf(c[t][reg]) : 0.f;
                l_acc[reg] += p;
                const int col = t * 16 + fr;
                myP[row * 64 + (((col >> 3) ^ (row & 7)) << 3) + (col & 7)] = f2bs(p);
            }
        }

        short8 pf0 = *(const short8*)&myP[fr * 64 + ((g       ^ (fr & 7)) << 3)];
        short8 pf1 = *(const short8*)&myP[fr * 64 + (((g + 4) ^ (fr & 7)) << 3)];
#pragma unroll
        for (int n = 0; n < 4; ++n) {
            short8 vf0 = *(const short8*)&Vs[(n * 16 + fr) * 64 + ((g       ^ (fr & 7)) << 3)];
            short8 vf1 = *(const short8*)&Vs[(n * 16 + fr) * 64 + (((g + 4) ^ (fr & 7)) << 3)];
            o[n] = __builtin_amdgcn_mfma_f32_16x16x32_bf16(pf0, vf0, o[n], 0, 0, 0);
            o[n] = __builtin_amdgcn_mfma_f32_16x16x32_bf16(pf1, vf1, o[n], 0, 0, 0);
        }
    }

    float inv[4];
#pragma unroll
    for (int reg = 0; reg < 4; ++reg) {
        float l = l_acc[reg];
#pragma unroll
        for (int off = 1; off < 16; off <<= 1) l += __shfl_xor(l, off);
        inv[reg] = 1.f / fmaxf(l, 1e-38f);
    }
#pragma unroll
    for (int n = 0; n < 4; ++n) {
#pragma unroll
        for (int reg = 0; reg < 4; ++reg) {
            const int q = q0 + g * 4 + reg;
            attn[((size_t)(b_ * SS + q)) * DD + h_ * HD + n * 16 + fr] =
                __float2bfloat16(o[n][reg] * inv[reg]);
        }
    }
}

// ---------------------------------------------------------------------------
extern "C" void kernel_launch(void* const* d_in, const int* in_sizes, int n_in,
                              void* d_out, int out_size, void* d_ws, size_t ws_size,
                              hipStream_t stream) {
    const float* x   = (const float*)d_in[0];
    const int*   pad = (const int*)  d_in[1];
    const float* Wq  = (const float*)d_in[2];
    const float* bq  = (const float*)d_in[3];
    const float* Wk  = (const float*)d_in[4];
    const float* bk  = (const float*)d_in[5];
    const float* Wv  = (const float*)d_in[6];
    const float* bv  = (const float*)d_in[7];
    const float* Wo  = (const float*)d_in[8];
    const float* bo  = (const float*)d_in[9];
    float* out = (float*)d_out;                  // fp32 output

    const size_t NELEM = (size_t)BB * HH * SS * HD;  // 4,194,304
    bf16* Qh   = (bf16*)d_ws;
    bf16* Kh   = Qh + NELEM;
    bf16* VT   = Kh + NELEM;
    bf16* attn = VT + NELEM;
    // Scratch in d_out (16.78 MB): Wcat 6.29 MB + Xb 8.39 MB, both consumed
    // before o_gemm2 overwrites d_out with the final fp32 result.
    short* Wcat = (short*)d_out;
    short* Xb   = (short*)d_out + (size_t)NQKV * DD;
    short* Wob  = (short*)Qh;                    // scratch in ws after flash

    static bool qkv8_init = false;
    if (!qkv8_init) {
        hipFuncSetAttribute(reinterpret_cast<const void*>(qkv_gemm8),
                            hipFuncAttributeMaxDynamicSharedMemorySize, 131072);
        qkv8_init = true;
    }

    convert_wcat<<<768, 256, 0, stream>>>(Wq, Wk, Wv, Wcat);
    convert_x<<<1024, 256, 0, stream>>>(x, Xb);

    qkv_gemm8<<<192, 512, 131072, stream>>>(Xb, Wcat, bq, bk, bv, Qh, Kh, VT);

    flash_mfma5<<<BB * HH * 32, 256, 0, stream>>>(Qh, Kh, VT, pad, attn);

    convert_w<<<512, 256, 0, stream>>>(Wo, Wob);

    dim3 go(MM / 128, DD / 128);
    o_gemm2<<<go, 256, 0, stream>>>((const short*)attn, Wob, bo, out);
}

// Round 4
// 226.752 us; speedup vs baseline: 1.0033x; 1.0033x over previous
//
#include <hip/hip_runtime.h>
#include <hip/hip_bf16.h>

// Problem constants (reference: B=2, S=2048, D=1024, H=16, HD=64)
#define BB 2
#define SS 2048
#define DD 1024
#define HH 16
#define HD 64
#define MM (BB * SS)   // 4096 rows in all GEMMs
#define NQKV 3072      // fused QKV output columns

typedef __attribute__((ext_vector_type(8))) short short8;   // 8 x bf16 frag
typedef __attribute__((ext_vector_type(4))) short s16x4;
typedef __attribute__((ext_vector_type(4))) float floatx4;  // MFMA C/D frag
typedef __attribute__((ext_vector_type(4))) float f32x4;
using bf16 = __hip_bfloat16;

__device__ __forceinline__ float b2f(bf16 x) { return __bfloat162float(x); }
__device__ __forceinline__ short f2bs(float x) {
    bf16 h = __float2bfloat16(x);
    return *reinterpret_cast<short*>(&h);
}
__device__ __forceinline__ float bs2f(short s) {
    bf16 h; *reinterpret_cast<short*>(&h) = s; return __bfloat162float(h);
}

// LDS tiles addressed in 16B chunks (8 shorts), XOR swizzle (chunk ^ (row&7)).
// Measured SQ_LDS_BANK_CONFLICT == 0 with this pattern.
__device__ __forceinline__ int lds_off(int row, int chunk) {
    return row * 64 + ((chunk ^ (row & 7)) * 8);
}

// Direct global->LDS async copy, 16B per lane. LDS dest is wave-uniform base
// + lane*16 (linear); the XOR swizzle is applied on the GLOBAL source address.
#define GL16(gp, lp)                                                        \
    __builtin_amdgcn_global_load_lds(                                       \
        (const __attribute__((address_space(1))) void*)(gp),                \
        (__attribute__((address_space(3))) void*)(lp), 16, 0, 0)

// ---------------------------------------------------------------------------
// Weight / input converters (unchanged).
// ---------------------------------------------------------------------------
__global__ __launch_bounds__(256) void convert_wcat(
    const float* __restrict__ Wq, const float* __restrict__ Wk,
    const float* __restrict__ Wv, short* __restrict__ dst)
{
    const int stride = gridDim.x * blockDim.x;
    for (int i = blockIdx.x * blockDim.x + threadIdx.x; i < NQKV * DD / 4; i += stride) {
        const int elem = i * 4;
        const int z    = elem >> 20;
        const int off  = elem & 0xFFFFF;
        const float* src = (z == 0) ? Wq : (z == 1) ? Wk : Wv;
        f32x4 v = *(const f32x4*)(src + off);
        s16x4 o; o[0] = f2bs(v[0]); o[1] = f2bs(v[1]); o[2] = f2bs(v[2]); o[3] = f2bs(v[3]);
        *(s16x4*)(dst + elem) = o;
    }
}

__global__ __launch_bounds__(256) void convert_w(
    const float* __restrict__ W, short* __restrict__ dst)
{
    const int stride = gridDim.x * blockDim.x;
    for (int i = blockIdx.x * blockDim.x + threadIdx.x; i < DD * DD / 4; i += stride) {
        f32x4 v = *(const f32x4*)(W + i * 4);
        s16x4 o; o[0] = f2bs(v[0]); o[1] = f2bs(v[1]); o[2] = f2bs(v[2]); o[3] = f2bs(v[3]);
        *(s16x4*)(dst + i * 4) = o;
    }
}

__global__ __launch_bounds__(256) void convert_x(
    const float* __restrict__ X, short* __restrict__ dst)
{
    const int stride = gridDim.x * blockDim.x;
    for (int i = blockIdx.x * blockDim.x + threadIdx.x; i < MM * DD / 4; i += stride) {
        f32x4 v = *(const f32x4*)(X + i * 4);
        s16x4 o; o[0] = f2bs(v[0]); o[1] = f2bs(v[1]); o[2] = f2bs(v[2]); o[3] = f2bs(v[3]);
        *(s16x4*)(dst + i * 4) = o;
    }
}

// ---------------------------------------------------------------------------
// Fused QKV GEMM, r16: 8-phase with REGISTER-RESIDENT fragments (r15 read the
// same frags twice; 96 ds_read_b128/iter/wave -> 48). Per K-tile:
//   p1 (MH0,NH0): load A.h0 (8 reads) + B.h0 (4)     | 16 MFMA
//   p2 (MH0,NH1): load B.h1 (4)   [A.h0 resident]    | 16 MFMA
//   p3 (MH1,NH0): load A.h1 (8)   [B.h0 resident]    | 16 MFMA
//   p4 (MH1,NH1): no reads        [A.h1,B.h1 res.]   | 16 MFMA
// No explicit lgkmcnt(0): reads are compiler-visible, so fine-grained
// per-MFMA lgkm waits overlap the read burst with early MFMAs (m97 finding).
// Stage schedule + vmcnt(4) gates identical to r15 (passing). Re-verified:
// register residency only moves last-read phases EARLIER (A.h0/B.h0 -> p1,
// B.h1 -> p2, A.h1 -> p3), so every stage window widens; gate-landing
// proofs unchanged (p4 gate lands buf1's tile before p5; p8 gate lands
// buf0's tile before next p1).
// ---------------------------------------------------------------------------
template <int D, int MH, int NH, bool LA, bool LB, class Stage, class Tail>
__device__ __forceinline__ void phase8(
    const short* As, const short* Bs, int wm, int wn, int fr, int g,
    short8 (&af)[4][2], short8 (&bf)[2][2][2],
    floatx4 (&acc)[8][4], Stage&& stage, Tail&& tail)
{
    const short* Ad = As + D * (256 * 64);
    const short* Bd = Bs + D * (256 * 64);
    // Read order: af[0] first, then B, then af[1..3] — so the first MFMAs'
    // operands arrive earliest under fine-grained lgkm waits.
    if (LA) {
#pragma unroll
        for (int kk = 0; kk < 2; ++kk)
            af[0][kk] = *(const short8*)&Ad[lds_off(MH * 128 + wm * 64 + fr, kk * 4 + g)];
    }
    if (LB) {
#pragma unroll
        for (int u = 0; u < 2; ++u)
#pragma unroll
            for (int kk = 0; kk < 2; ++kk)
                bf[NH][u][kk] = *(const short8*)&Bd[lds_off(NH * 128 + wn * 32 + u * 16 + fr, kk * 4 + g)];
    }
    if (LA) {
#pragma unroll
        for (int t = 1; t < 4; ++t)
#pragma unroll
            for (int kk = 0; kk < 2; ++kk)
                af[t][kk] = *(const short8*)&Ad[lds_off(MH * 128 + wm * 64 + t * 16 + fr, kk * 4 + g)];
    }
    stage();
    __builtin_amdgcn_s_barrier();
    __builtin_amdgcn_s_setprio(1);
#pragma unroll
    for (int t = 0; t < 4; ++t)
#pragma unroll
        for (int u = 0; u < 2; ++u) {
            acc[MH * 4 + t][NH * 2 + u] = __builtin_amdgcn_mfma_f32_16x16x32_bf16(
                af[t][0], bf[NH][u][0], acc[MH * 4 + t][NH * 2 + u], 0, 0, 0);
            acc[MH * 4 + t][NH * 2 + u] = __builtin_amdgcn_mfma_f32_16x16x32_bf16(
                af[t][1], bf[NH][u][1], acc[MH * 4 + t][NH * 2 + u], 0, 0, 0);
        }
    __builtin_amdgcn_s_setprio(0);
    tail();
    __builtin_amdgcn_s_barrier();
}

__global__ __launch_bounds__(512, 2) void qkv_gemm8(
    const short* __restrict__ Xb, const short* __restrict__ Wcat,
    const float* __restrict__ bq, const float* __restrict__ bk, const float* __restrict__ bv,
    bf16* __restrict__ outQ, bf16* __restrict__ outK, bf16* __restrict__ outV)
{
    extern __shared__ short lds[];
    short* As = lds;                   // [2][256*64]
    short* Bs = lds + 2 * 256 * 64;    // [2][256*64]

    const int tid  = threadIdx.x;
    const int lane = tid & 63;
    const int wave = tid >> 6;     // 0..7
    const int wm   = wave >> 2;    // 0..1  (M sub-block within a quadrant)
    const int wn   = wave & 3;     // 0..3  (N sub-block within a quadrant)
    const int g    = lane >> 4;
    const int fr   = lane & 15;

    // XCD-aware swizzle: 192 blocks, 24 per XCD chunk (bijective, 192%8==0).
    const int sw = (blockIdx.x & 7) * 24 + (blockIdx.x >> 3);
    const int m0 = (sw % 16) * 256;
    const int n0 = (sw / 16) * 256;

    const int srow8 = lane >> 3;            // 0..7
    const int schk  = (lane & 7) ^ srow8;   // pre-swizzled source chunk

    const short* aglB = Xb   + (size_t)(m0 + srow8) * DD + schk * 8;
    const short* bglB = Wcat + (size_t)(n0 + srow8) * DD + schk * 8;

    // stage one half (128 rows x 64 k) of A or B into buf d, half h, K-tile kt.
    auto stageA = [&](int d, int h, int kt) {
#pragma unroll
        for (int j = 0; j < 2; ++j) {
            const int r = h * 128 + wave * 16 + j * 8;
            GL16(aglB + (size_t)r * DD + kt * 64, As + d * (256 * 64) + r * 64);
        }
    };
    auto stageB = [&](int d, int h, int kt) {
#pragma unroll
        for (int j = 0; j < 2; ++j) {
            const int r = h * 128 + wave * 16 + j * 8;
            GL16(bglB + (size_t)r * DD + kt * 64, Bs + d * (256 * 64) + r * 64);
        }
    };

    floatx4 acc[8][4];
#pragma unroll
    for (int i = 0; i < 8; ++i)
#pragma unroll
        for (int j = 0; j < 4; ++j) acc[i][j] = (floatx4){0.f, 0.f, 0.f, 0.f};

    // Prologue: fully stage tiles 0 (buf0) and 1 (buf1).
    stageA(0, 0, 0); stageA(0, 1, 0); stageB(0, 0, 0); stageB(0, 1, 0);
    stageA(1, 0, 1); stageA(1, 1, 1); stageB(1, 0, 1); stageB(1, 1, 1);
    asm volatile("s_waitcnt vmcnt(0)" ::: "memory");
    __builtin_amdgcn_s_barrier();

    auto nop = [] {};
    auto vm4 = [] { asm volatile("s_waitcnt vmcnt(4)" ::: "memory"); };

    for (int it = 0; it < 8; ++it) {
        const int t1 = (2 * it + 1) & 15;
        const int s2 = (2 * it + 2) & 15;   // wraps harmlessly on last iter
        const int s3 = (2 * it + 3) & 15;
        short8 af[4][2];       // current A-half frags (reloaded per MH)
        short8 bf[2][2][2];    // both B-half frags, resident per K-tile
        // ---- buf0, K-tile 2it ----
        phase8<0, 0, 0, true,  true >(As, Bs, wm, wn, fr, g, af, bf, acc,
                                      [&] { if (it) stageA(1, 1, t1); }, nop);
        phase8<0, 0, 1, false, true >(As, Bs, wm, wn, fr, g, af, bf, acc,
                                      [&] { if (it) stageB(1, 1, t1); }, nop);
        phase8<0, 1, 0, true,  false>(As, Bs, wm, wn, fr, g, af, bf, acc,
                                      [&] { stageA(0, 0, s2); }, nop);
        phase8<0, 1, 1, false, false>(As, Bs, wm, wn, fr, g, af, bf, acc,
                                      [&] { stageB(0, 0, s2); }, vm4);
        // ---- buf1, K-tile 2it+1 ----
        phase8<1, 0, 0, true,  true >(As, Bs, wm, wn, fr, g, af, bf, acc,
                                      [&] { stageA(0, 1, s2); }, nop);
        phase8<1, 0, 1, false, true >(As, Bs, wm, wn, fr, g, af, bf, acc,
                                      [&] { stageB(0, 1, s2); }, nop);
        phase8<1, 1, 0, true,  false>(As, Bs, wm, wn, fr, g, af, bf, acc,
                                      [&] { stageA(1, 0, s3); }, nop);
        phase8<1, 1, 1, false, false>(As, Bs, wm, wn, fr, g, af, bf, acc,
                                      [&] { stageB(1, 0, s3); }, vm4);
    }

    // Epilogue: quadrant-major index mapping (validated r15).
#pragma unroll
    for (int nt = 0; nt < 4; ++nt) {
        const int n  = n0 + (nt >> 1) * 128 + wn * 32 + (nt & 1) * 16 + fr;
        const int z  = n >> 10;
        const int nn = n & 1023;
        const int h_ = nn >> 6;
        const int d_ = nn & 63;
        const float biasv = ((z == 0) ? bq : (z == 1) ? bk : bv)[nn];
        bf16* outp = (z == 0) ? outQ : (z == 1) ? outK : outV;
#pragma unroll
        for (int mt = 0; mt < 8; ++mt) {
#pragma unroll
            for (int reg = 0; reg < 4; ++reg) {
                const int m  = m0 + (mt >> 2) * 128 + wm * 64 + (mt & 3) * 16 + g * 4 + reg;
                const int b_ = m >> 11;
                const int s_ = m & (SS - 1);
                const float v = acc[mt][nt][reg] + biasv;
                size_t off;
                if (z == 2) off = ((size_t)((b_ * HH + h_) * HD + d_)) * SS + s_;  // V^T
                else        off = ((size_t)((b_ * HH + h_) * SS + s_)) * HD + d_;  // Q,K
                outp[off] = __float2bfloat16(v);
            }
        }
    }
}

// ---------------------------------------------------------------------------
// Output projection (r13 structure, unchanged: global_load_lds, 128^2 tile).
// ---------------------------------------------------------------------------
__global__ __launch_bounds__(256) void o_gemm2(
    const short* __restrict__ A, const short* __restrict__ Wob,
    const float* __restrict__ bias, float* __restrict__ out)
{
    __shared__ short As[128 * 64];
    __shared__ short Bs[128 * 64];

    const int tid  = threadIdx.x;
    const int lane = tid & 63;
    const int wave = tid >> 6;
    const int wm   = wave & 1;
    const int wn   = wave >> 1;
    const int g    = lane >> 4;
    const int fr   = lane & 15;

    const int m0 = blockIdx.x * 128;
    const int n0 = blockIdx.y * 128;

    const int srow = wave * 32 + (lane >> 3);
    const int schk = (lane & 7) ^ (lane >> 3);
    const short* agl = A   + (size_t)(m0 + srow) * DD + schk * 8;
    const short* bgl = Wob + (size_t)(n0 + srow) * DD + schk * 8;
    short* alds = &As[wave * 32 * 64];
    short* blds = &Bs[wave * 32 * 64];

    floatx4 acc[4][4];
#pragma unroll
    for (int i = 0; i < 4; ++i)
#pragma unroll
        for (int j = 0; j < 4; ++j) acc[i][j] = (floatx4){0.f, 0.f, 0.f, 0.f};

    for (int kb = 0; kb < DD; kb += 64) {
        __syncthreads();
#pragma unroll
        for (int j = 0; j < 4; ++j) {
            GL16(agl + kb + j * 8 * DD, alds + j * 8 * 64);
            GL16(bgl + kb + j * 8 * DD, blds + j * 8 * 64);
        }
        __syncthreads();

#pragma unroll
        for (int kk = 0; kk < 2; ++kk) {
            const int kc = kk * 4 + g;
            short8 af[4], bf[4];
#pragma unroll
            for (int t = 0; t < 4; ++t) {
                af[t] = *(const short8*)&As[lds_off(wm * 64 + t * 16 + fr, kc)];
                bf[t] = *(const short8*)&Bs[lds_off(wn * 64 + t * 16 + fr, kc)];
            }
#pragma unroll
            for (int mt = 0; mt < 4; ++mt)
#pragma unroll
                for (int nt = 0; nt < 4; ++nt)
                    acc[mt][nt] = __builtin_amdgcn_mfma_f32_16x16x32_bf16(
                        af[mt], bf[nt], acc[mt][nt], 0, 0, 0);
        }
    }

#pragma unroll
    for (int nt = 0; nt < 4; ++nt) {
        const int n = n0 + wn * 64 + nt * 16 + fr;
        const float biasv = bias[n];
#pragma unroll
        for (int mt = 0; mt < 4; ++mt) {
#pragma unroll
            for (int reg = 0; reg < 4; ++reg) {
                const int m = m0 + wm * 64 + mt * 16 + g * 4 + reg;
                out[(size_t)m * DD + n] = acc[mt][nt][reg] + biasv;
            }
        }
    }
}

// ---------------------------------------------------------------------------
// MFMA flash attention v5 (unchanged).
// ---------------------------------------------------------------------------
__global__ __launch_bounds__(256) void flash_mfma5(
    const bf16* __restrict__ Qh,   // [B,H,S,HD]
    const bf16* __restrict__ Kh,   // [B,H,S,HD]
    const bf16* __restrict__ VT,   // [B,H,HD,S]
    const int*  __restrict__ pad,  // [B,S] int32, nonzero = masked key
    bf16* __restrict__ attn)       // [B,S,D]
{
    __shared__ short Ks[64 * 64];
    __shared__ short Vs[64 * 64];
    __shared__ short Pld[4][16 * 64];

    const int tid  = threadIdx.x;
    const int lane = tid & 63;
    const int wave = tid >> 6;
    const int xcd = blockIdx.x & 7;
    const int idx = blockIdx.x >> 3;
    const int bh  = (xcd << 2) | (idx & 3);
    const int qt  = 31 - (idx >> 2);
    const int q0  = qt * 64 + wave * 16;
    const int b_  = bh >> 4;
    const int h_  = bh & 15;

    const int g  = lane >> 4;
    const int fr = lane & 15;
    const int k8 = g * 8;

    short* myP = Pld[wave];

    const bf16* qbase = Qh + ((size_t)bh * SS + q0 + fr) * HD + k8;
    short8 qf[2];
#pragma unroll
    for (int hh = 0; hh < 2; ++hh) {
        short8 rawq = *(const short8*)((const short*)qbase + hh * 32);
#pragma unroll
        for (int j = 0; j < 8; ++j) qf[hh][j] = f2bs(bs2f(rawq[j]) * 0.125f);
    }

    const int* padrow = pad + b_ * SS;
    const short* kbh = (const short*)(Kh + (size_t)bh * SS * HD);
    const short* vbh = (const short*)(VT + (size_t)bh * HD * SS);

    const int sr = tid >> 2;
    const int cp = (tid & 3) * 2;

    floatx4 o[4] = {{0,0,0,0},{0,0,0,0},{0,0,0,0},{0,0,0,0}};
    float l_acc[4] = {0.f, 0.f, 0.f, 0.f};

    const int kend = qt * 64 + 63;
    for (int kb = 0; kb <= kend; kb += 64) {
        __syncthreads();
        {
            const short* gk = kbh + (size_t)(kb + sr) * HD + cp * 8;
            *(short8*)&Ks[lds_off(sr, cp)]     = *(const short8*)gk;
            *(short8*)&Ks[lds_off(sr, cp + 1)] = *(const short8*)(gk + 8);
            const short* gv = vbh + (size_t)sr * SS + kb + cp * 8;
            *(short8*)&Vs[lds_off(sr, cp)]     = *(const short8*)gv;
            *(short8*)&Vs[lds_off(sr, cp + 1)] = *(const short8*)(gv + 8);
        }
        __syncthreads();

        floatx4 c[4];
#pragma unroll
        for (int t = 0; t < 4; ++t) {
            short8 kf0 = *(const short8*)&Ks[(t * 16 + fr) * 64 + ((g       ^ (fr & 7)) << 3)];
            short8 kf1 = *(const short8*)&Ks[(t * 16 + fr) * 64 + (((g + 4) ^ (fr & 7)) << 3)];
            floatx4 cc = {0, 0, 0, 0};
            cc = __builtin_amdgcn_mfma_f32_16x16x32_bf16(qf[0], kf0, cc, 0, 0, 0);
            cc = __builtin_amdgcn_mfma_f32_16x16x32_bf16(qf[1], kf1, cc, 0, 0, 0);
            c[t] = cc;
        }

        bool pm[4];
#pragma unroll
        for (int t = 0; t < 4; ++t) pm[t] = (padrow[kb + t * 16 + fr] != 0);

#pragma unroll
        for (int reg = 0; reg < 4; ++reg) {
            const int q   = q0 + g * 4 + reg;
            const int row = g * 4 + reg;
#pragma unroll
            for (int t = 0; t < 4; ++t) {
                const int key = kb + t * 16 + fr;
                const float p = (key <= q && !pm[t]) ? __expf(c[t][reg]) : 0.f;
                l_acc[reg] += p;
                const int col = t * 16 + fr;
                myP[row * 64 + (((col >> 3) ^ (row & 7)) << 3) + (col & 7)] = f2bs(p);
            }
        }

        short8 pf0 = *(const short8*)&myP[fr * 64 + ((g       ^ (fr & 7)) << 3)];
        short8 pf1 = *(const short8*)&myP[fr * 64 + (((g + 4) ^ (fr & 7)) << 3)];
#pragma unroll
        for (int n = 0; n < 4; ++n) {
            short8 vf0 = *(const short8*)&Vs[(n * 16 + fr) * 64 + ((g       ^ (fr & 7)) << 3)];
            short8 vf1 = *(const short8*)&Vs[(n * 16 + fr) * 64 + (((g + 4) ^ (fr & 7)) << 3)];
            o[n] = __builtin_amdgcn_mfma_f32_16x16x32_bf16(pf0, vf0, o[n], 0, 0, 0);
            o[n] = __builtin_amdgcn_mfma_f32_16x16x32_bf16(pf1, vf1, o[n], 0, 0, 0);
        }
    }

    float inv[4];
#pragma unroll
    for (int reg = 0; reg < 4; ++reg) {
        float l = l_acc[reg];
#pragma unroll
        for (int off = 1; off < 16; off <<= 1) l += __shfl_xor(l, off);
        inv[reg] = 1.f / fmaxf(l, 1e-38f);
    }
#pragma unroll
    for (int n = 0; n < 4; ++n) {
#pragma unroll
        for (int reg = 0; reg < 4; ++reg) {
            const int q = q0 + g * 4 + reg;
            attn[((size_t)(b_ * SS + q)) * DD + h_ * HD + n * 16 + fr] =
                __float2bfloat16(o[n][reg] * inv[reg]);
        }
    }
}

// ---------------------------------------------------------------------------
extern "C" void kernel_launch(void* const* d_in, const int* in_sizes, int n_in,
                              void* d_out, int out_size, void* d_ws, size_t ws_size,
                              hipStream_t stream) {
    const float* x   = (const float*)d_in[0];
    const int*   pad = (const int*)  d_in[1];
    const float* Wq  = (const float*)d_in[2];
    const float* bq  = (const float*)d_in[3];
    const float* Wk  = (const float*)d_in[4];
    const float* bk  = (const float*)d_in[5];
    const float* Wv  = (const float*)d_in[6];
    const float* bv  = (const float*)d_in[7];
    const float* Wo  = (const float*)d_in[8];
    const float* bo  = (const float*)d_in[9];
    float* out = (float*)d_out;                  // fp32 output

    const size_t NELEM = (size_t)BB * HH * SS * HD;  // 4,194,304
    bf16* Qh   = (bf16*)d_ws;
    bf16* Kh   = Qh + NELEM;
    bf16* VT   = Kh + NELEM;
    bf16* attn = VT + NELEM;
    // Scratch in d_out (16.78 MB): Wcat 6.29 MB + Xb 8.39 MB, both consumed
    // before o_gemm2 overwrites d_out with the final fp32 result.
    short* Wcat = (short*)d_out;
    short* Xb   = (short*)d_out + (size_t)NQKV * DD;
    short* Wob  = (short*)Qh;                    // scratch in ws after flash

    static bool qkv8_init = false;
    if (!qkv8_init) {
        hipFuncSetAttribute(reinterpret_cast<const void*>(qkv_gemm8),
                            hipFuncAttributeMaxDynamicSharedMemorySize, 131072);
        qkv8_init = true;
    }

    convert_wcat<<<768, 256, 0, stream>>>(Wq, Wk, Wv, Wcat);
    convert_x<<<1024, 256, 0, stream>>>(x, Xb);

    qkv_gemm8<<<192, 512, 131072, stream>>>(Xb, Wcat, bq, bk, bv, Qh, Kh, VT);

    flash_mfma5<<<BB * HH * 32, 256, 0, stream>>>(Qh, Kh, VT, pad, attn);

    convert_w<<<512, 256, 0, stream>>>(Wo, Wob);

    dim3 go(MM / 128, DD / 128);
    o_gemm2<<<go, 256, 0, stream>>>((const short*)attn, Wob, bo, out);
}